// Round 8
// baseline (627.923 us; speedup 1.0000x reference)
//
#include <hip/hip_runtime.h>

#define HID   128
#define GATES 512
#define BATCH 256
#define SEQ   512
#define INSZ  10
#define MB    16                 // batch rows per block (MFMA M)
#define NBLK  (BATCH / MB)       // 16 producer blocks + 16 consumer blocks
#define NTHR  512                // 8 waves
#define HSTR  136                // fp16 row stride for h buffers (bank-conflict pad, 16B-aligned rows)
#define XSTR  40                 // fp16 row stride for x staging (K padded 10->32, +8 pad)
#define XCH   8                  // x chunk (steps) phase A
#define HCH   4                  // h1 chunk (steps) phase B
#define PCH   8                  // producer publish granularity (steps per flag update)

typedef _Float16 half8  __attribute__((ext_vector_type(8)));
typedef _Float16 half2v __attribute__((ext_vector_type(2)));
typedef float    floatx4 __attribute__((ext_vector_type(4)));

#define MFMA16(A, B, C) __builtin_amdgcn_mfma_f32_16x16x32_f16(A, B, C, 0, 0, 0)

// Gate scales folded into weights+biases: accumulator holds the ready exp2 arg.
//   i,f,o: a = -log2e * pre      -> sigm = rcp(1+exp2(a))
//   g:     a = -2*log2e * pre    -> tanh = (1-exp2(a))/(1+exp2(a))
// Fused-product forms (one rcp per product; e's clamped to avoid inf*0=NaN):
//   sigm(i)*tanh(g) = (1-eg) * rcp((1+ei)*(1+eg))
//   sigm(o)*tanh(c) = (1-ec) * rcp((1+eo)*(1+ec))
#define KSIG  (-1.4426950408889634f)
#define KTAN  (-2.8853900817779268f)
#define ECLAMP 1e15f

// convert 8 consecutive f32 weights (pre-scaled) to a half8 B-fragment
__device__ __forceinline__ half8 load_wfrag(const float* rowbase, int k0, float scale)
{
    const float4* p = (const float4*)(rowbase + k0);
    float4 a = p[0], b = p[1];
    half8 r;
    r[0] = (_Float16)(a.x * scale); r[1] = (_Float16)(a.y * scale);
    r[2] = (_Float16)(a.z * scale); r[3] = (_Float16)(a.w * scale);
    r[4] = (_Float16)(b.x * scale); r[5] = (_Float16)(b.y * scale);
    r[6] = (_Float16)(b.z * scale); r[7] = (_Float16)(b.w * scale);
    return r;
}

// ---- LDS layout (bytes) ----  (R4 layout)
// Producer: xs [2][XCH][MB][XSTR] fp16 @0 (20480 B), h0 [2][MB][HSTR] fp16 @20480 (8704 B)
// Consumer: h1c [2][HCH][MB][HSTR] fp16 @0 (34816 B), h2 [2][MB][HSTR] fp16 @34816 (8704 B)
// Final:    h2f [MB][132] f32 @0 (8448 B; only overlaps h1c buf0, dead by t=511)
#define XBUF_HALFS (XCH * MB * XSTR)      // 5120
#define H1C_BUF_HALFS (HCH * MB * HSTR)   // 8704
#define H0_OFF  20480
#define H2_OFF  34816
#define LDS_BYTES 43520

// Chunk-flag wait: relaxed device-scope spin, then one acquire to order the
// subsequent h1 loads against the producer's release. lastf caches the last
// observed value so steady-state polls are a register compare (no memory op).
__device__ __forceinline__ int wait_flag(int* flagp, int needed, int lastf)
{
    if (lastf >= needed) return lastf;
    int f = __hip_atomic_load(flagp, __ATOMIC_RELAXED, __HIP_MEMORY_SCOPE_AGENT);
    while (f < needed) {
        __builtin_amdgcn_s_sleep(2);
        f = __hip_atomic_load(flagp, __ATOMIC_RELAXED, __HIP_MEMORY_SCOPE_AGENT);
    }
    (void)__hip_atomic_load(flagp, __ATOMIC_ACQUIRE, __HIP_MEMORY_SCOPE_AGENT);
    return f;
}

__global__ __launch_bounds__(NTHR, 2)
void lstm_fused(const float* __restrict__ x,
                const float* __restrict__ w_ih0, const float* __restrict__ w_hh0,
                const float* __restrict__ b_ih0, const float* __restrict__ b_hh0,
                const float* __restrict__ w_ih1, const float* __restrict__ w_hh1,
                const float* __restrict__ b_ih1, const float* __restrict__ b_hh1,
                const float* __restrict__ fc_w,  const float* __restrict__ fc_b,
                float* __restrict__ out, _Float16* __restrict__ h1w_all)
{
    const int tid  = threadIdx.x;
    const int lane = tid & 63;
    const int wv   = tid >> 6;        // wave 0..7 -> hidden cols [16wv,16wv+16)
    const int m16  = lane & 15;       // MFMA row (batch) / col-in-tile
    const int quad = lane >> 4;       // 0..3
    const int col  = (wv << 4) + m16; // hidden col 0..127

    const bool producer = (blockIdx.x < NBLK);
    const int  pb = producer ? blockIdx.x : blockIdx.x - NBLK;  // batch-tile id
    const int  b0 = pb * MB;

    __shared__ __align__(16) char lds[LDS_BYTES];
    _Float16* xs  = (_Float16*)lds;
    _Float16* h0s = (_Float16*)(lds + H0_OFF);
    _Float16* h1c = (_Float16*)lds;
    _Float16* h2s = (_Float16*)(lds + H2_OFF);
    float*    h2f = (float*)lds;

    _Float16* h1w = h1w_all + (size_t)pb * SEQ * MB * HID;
    // flag parked inside this tile's out rows (host memsets out to 0 pre-launch);
    // consumer pb's FC epilogue overwrites it only after its last poll.
    int* flagp = (int*)out + pb * (MB * 10);

    const float gsc[4] = {KSIG, KSIG, KTAN, KSIG};   // i, f, g, o

    if (producer) {
        // ---------------- layer-0 weight fragments (pre-scaled) ----------------
        half8 Whh0f[4][4];   // [gate][kslice]  B[k][n]: n=lane&15 within tile, k=32ks+8quad+j
        half8 Wih0f[4];      // K=32 padded from 10
        float bias0[4];
#pragma unroll
        for (int g = 0; g < 4; ++g) {
            const int gr = g * HID + col;
            const float sc = gsc[g];
            bias0[g] = (b_ih0[gr] + b_hh0[gr]) * sc;
#pragma unroll
            for (int ks = 0; ks < 4; ++ks)
                Whh0f[g][ks] = load_wfrag(w_hh0 + (size_t)gr * HID, ks * 32 + quad * 8, sc);
            half8 r;
#pragma unroll
            for (int j = 0; j < 8; ++j) {
                int k = quad * 8 + j;
                r[j] = (k < INSZ) ? (_Float16)(w_ih0[gr * INSZ + k] * sc) : (_Float16)0.0f;
            }
            Wih0f[g] = r;
        }

        // zero x (both bufs incl. k>=10 pad) and h0 (both bufs)
        for (int i = tid; i < (H0_OFF + 8704) / 4; i += NTHR) ((int*)lds)[i] = 0;

        // stage x chunk 0 (threads 0..127, one (step,batch) row each)
        if (tid < 128) {
            const int sr = tid >> 4, mr = tid & 15;
            const float2* xp = (const float2*)(x + ((size_t)(b0 + mr) * SEQ + sr) * INSZ);
            _Float16* dst = xs + (sr * MB + mr) * XSTR;
#pragma unroll
            for (int p = 0; p < 5; ++p) {
                float2 v = xp[p];
                half2v h; h[0] = (_Float16)v.x; h[1] = (_Float16)v.y;
                *(half2v*)(dst + 2 * p) = h;
            }
        }
        __syncthreads();

        // ---------------- layer-0 recurrence ----------------
        float c0[4] = {0.f, 0.f, 0.f, 0.f};
        float2 xr[5];
        floatx4 xg[4][4];    // [slot][gate] precomputed bias + x-part (burst), then hh-accumulated

        // burst: precompute the x-gates for steps base..base+3 (no recurrence dep,
        // deep MFMA pipeline, off the serial chain). slot k = (base+k)&3.
        auto xburst = [&](int base) {
            const _Float16* xb = xs + ((base >> 3) & 1) * XBUF_HALFS;
#pragma unroll
            for (int k = 0; k < 4; ++k) {
                half8 xa = *(const half8*)(xb + (((base & 7) + k) * MB + m16) * XSTR + quad * 8);
#pragma unroll
                for (int g = 0; g < 4; ++g) {
                    floatx4 a = {bias0[g], bias0[g], bias0[g], bias0[g]};
                    a = MFMA16(xa, Wih0f[g], a);
                    xg[k][g] = a;
                }
            }
        };
        xburst(0);

        for (int tc = 0; tc < SEQ; tc += 8) {
#pragma unroll
            for (int s8 = 0; s8 < 8; ++s8) {
                const int t = tc + s8;
                const int sl = s8 & 3;            // xg slot (static after unroll)
                // prefetch next x chunk into regs at s8==0, commit to LDS at s8==2
                if (s8 == 0 && t + XCH < SEQ && tid < 128) {
                    const int sr = tid >> 4, mr = tid & 15;
                    const float2* xp = (const float2*)(x + ((size_t)(b0 + mr) * SEQ + (t + XCH + sr)) * INSZ);
#pragma unroll
                    for (int p = 0; p < 5; ++p) xr[p] = xp[p];
                }
                // hh-part: 4-deep dependent chain per gate, C-init = precomputed xg
                const _Float16* hb = h0s + (s8 & 1) * (MB * HSTR) + m16 * HSTR + quad * 8;
                half8 ha0 = *(const half8*)(hb);
                half8 ha1 = *(const half8*)(hb + 32);
                half8 ha2 = *(const half8*)(hb + 64);
                half8 ha3 = *(const half8*)(hb + 96);
#pragma unroll
                for (int g = 0; g < 4; ++g) {
                    floatx4 a = xg[sl][g];
                    a = MFMA16(ha0, Whh0f[g][0], a);
                    a = MFMA16(ha1, Whh0f[g][1], a);
                    a = MFMA16(ha2, Whh0f[g][2], a);
                    a = MFMA16(ha3, Whh0f[g][3], a);
                    xg[sl][g] = a;
                }
                if (s8 == 2 && t + 6 < SEQ && tid < 128) {
                    const int sr = tid >> 4, mr = tid & 15;
                    _Float16* dst = xs + (((t >> 3) + 1) & 1) * XBUF_HALFS + (sr * MB + mr) * XSTR;
#pragma unroll
                    for (int p = 0; p < 5; ++p) {
                        half2v h; h[0] = (_Float16)xr[p].x; h[1] = (_Float16)xr[p].y;
                        *(half2v*)(dst + 2 * p) = h;
                    }
                }
                // epilogue: C layout col=lane&15 (=our col), row=quad*4+e
                // fused-rcp activations: 5 exp2 + 3 rcp per element (was 5+5)
                _Float16* hw = h0s + ((s8 & 1) ^ 1) * (MB * HSTR);
#pragma unroll
                for (int e = 0; e < 4; ++e) {
                    float ef = __builtin_amdgcn_exp2f(xg[sl][1][e]);
                    float fv = __builtin_amdgcn_rcpf(1.0f + ef);
                    float ei = __builtin_amdgcn_exp2f(xg[sl][0][e]);
                    float eg = fminf(__builtin_amdgcn_exp2f(xg[sl][2][e]), ECLAMP);
                    float ivgv = (1.0f - eg) *
                                 __builtin_amdgcn_rcpf((1.0f + ei) * (1.0f + eg));
                    c0[e] = __builtin_fmaf(fv, c0[e], ivgv);
                    float eo = __builtin_amdgcn_exp2f(xg[sl][3][e]);
                    float ec = fminf(__builtin_amdgcn_exp2f(KTAN * c0[e]), ECLAMP);
                    float hv = (1.0f - ec) *
                               __builtin_amdgcn_rcpf((1.0f + eo) * (1.0f + ec));
                    _Float16 hh = (_Float16)hv;
                    const int row = quad * 4 + e;
                    hw[row * HSTR + col] = hh;
                    h1w[((size_t)t * MB + row) * HID + col] = hh;   // layer-1 input sequence
                }
                // burst the next 4 steps' x-gates (after epilogue consumed xg[3])
                if ((s8 == 3 || s8 == 7) && t + 4 < SEQ) xburst(t + 1);
                __syncthreads();
                // publish: syncthreads drained all waves' h1w stores for steps <= t
                if (s8 == 7 && tid == 0) {
                    __threadfence();   // XCD L2 writeback -> device-visible
                    __hip_atomic_store(flagp, t + 1, __ATOMIC_RELEASE, __HIP_MEMORY_SCOPE_AGENT);
                }
            }
        }
        return;
    }

    // ================= consumer: layer 1 =================
    half8 Wih1f[4][4], Whh1f[4][4];
    float bias1[4];
#pragma unroll
    for (int g = 0; g < 4; ++g) {
        const int gr = g * HID + col;
        const float sc = gsc[g];
        bias1[g] = (b_ih1[gr] + b_hh1[gr]) * sc;
#pragma unroll
        for (int ks = 0; ks < 4; ++ks) {
            Wih1f[g][ks] = load_wfrag(w_ih1 + (size_t)gr * HID, ks * 32 + quad * 8, sc);
            Whh1f[g][ks] = load_wfrag(w_hh1 + (size_t)gr * HID, ks * 32 + quad * 8, sc);
        }
    }
    // zero h2 state bufs
    for (int i = tid; i < 2176; i += NTHR) ((int*)(lds + H2_OFF))[i] = 0;

    int lastf = 0;
    lastf = wait_flag(flagp, 8, lastf);   // steps 0..7 available (need 0..3)

    // stage h1 chunk 0
#pragma unroll
    for (int r = 0; r < 2; ++r) {
        const int fi = tid + NTHR * r;         // 0..1023 -> 8 fp16 each
        const int ef = fi * 8;
        const int ss = ef >> 11, rem = ef & 2047;
        const int mm = rem >> 7, k0 = rem & 127;
        int4 v = *(const int4*)(h1w + ef);
        *(int4*)(h1c + (ss * MB + mm) * HSTR + k0) = v;
    }
    __syncthreads();

    floatx4 pg[4][4];    // [slot][gate] precomputed bias + p-part (burst), then q-accumulated

    // burst: xg1 = bias + h1[base+k] @ W_ih1^T for the 4 steps of a chunk.
    // 64 independent MFMAs, no barriers, off the serial chain.
    auto pburst = [&](int base) {
        const _Float16* sb = h1c + ((base >> 2) & 1) * H1C_BUF_HALFS;
#pragma unroll
        for (int k = 0; k < 4; ++k) {
            const _Float16* pp = sb + (k * MB + m16) * HSTR + quad * 8;
            half8 f0 = *(const half8*)(pp);
            half8 f1 = *(const half8*)(pp + 32);
            half8 f2 = *(const half8*)(pp + 64);
            half8 f3 = *(const half8*)(pp + 96);
#pragma unroll
            for (int g = 0; g < 4; ++g) {
                floatx4 a = {bias1[g], bias1[g], bias1[g], bias1[g]};
                a = MFMA16(f0, Wih1f[g][0], a);
                a = MFMA16(f1, Wih1f[g][1], a);
                a = MFMA16(f2, Wih1f[g][2], a);
                a = MFMA16(f3, Wih1f[g][3], a);
                pg[k][g] = a;
            }
        }
    };
    pburst(0);

    float c1[4] = {0.f, 0.f, 0.f, 0.f};
    int4 hr0, hr1;
    for (int tc = 0; tc < SEQ; tc += 4) {
#pragma unroll
        for (int s = 0; s < 4; ++s) {
            const int t = tc + s;
            if (s == 0 && t + HCH < SEQ) {
                lastf = wait_flag(flagp, t + 2 * HCH, lastf);   // producer done through step t+7
                const _Float16* src = h1w + (size_t)((t >> 2) + 1) * (HCH * MB * HID);
                hr0 = *(const int4*)(src + tid * 8);
                hr1 = *(const int4*)(src + (tid + NTHR) * 8);
            }
            // q-part: 4-deep dependent chain per gate, C-init = precomputed pg
            const _Float16* h2b = h2s + (s & 1) * (MB * HSTR) + m16 * HSTR + quad * 8;
            half8 q0 = *(const half8*)(h2b);
            half8 q1 = *(const half8*)(h2b + 32);
            half8 q2 = *(const half8*)(h2b + 64);
            half8 q3 = *(const half8*)(h2b + 96);
#pragma unroll
            for (int g = 0; g < 4; ++g) {
                floatx4 a = pg[s][g];
                a = MFMA16(q0, Whh1f[g][0], a);
                a = MFMA16(q1, Whh1f[g][1], a);
                a = MFMA16(q2, Whh1f[g][2], a);
                a = MFMA16(q3, Whh1f[g][3], a);
                pg[s][g] = a;
            }
            if (s == 2 && t + 2 < SEQ) {
                _Float16* dstb = h1c + (((t >> 2) + 1) & 1) * H1C_BUF_HALFS;
                int ef = tid * 8;
                int ss = ef >> 11, rem = ef & 2047, mm = rem >> 7, k0 = rem & 127;
                *(int4*)(dstb + (ss * MB + mm) * HSTR + k0) = hr0;
                ef = (tid + NTHR) * 8;
                ss = ef >> 11; rem = ef & 2047; mm = rem >> 7; k0 = rem & 127;
                *(int4*)(dstb + (ss * MB + mm) * HSTR + k0) = hr1;
            }
            // epilogue (fused-rcp activations, same as producer)
            _Float16* hw2 = h2s + ((s & 1) ^ 1) * (MB * HSTR);
#pragma unroll
            for (int e = 0; e < 4; ++e) {
                float ef2 = __builtin_amdgcn_exp2f(pg[s][1][e]);
                float fv = __builtin_amdgcn_rcpf(1.0f + ef2);
                float ei = __builtin_amdgcn_exp2f(pg[s][0][e]);
                float eg = fminf(__builtin_amdgcn_exp2f(pg[s][2][e]), ECLAMP);
                float ivgv = (1.0f - eg) *
                             __builtin_amdgcn_rcpf((1.0f + ei) * (1.0f + eg));
                c1[e] = __builtin_fmaf(fv, c1[e], ivgv);
                float eo = __builtin_amdgcn_exp2f(pg[s][3][e]);
                float ec = fminf(__builtin_amdgcn_exp2f(KTAN * c1[e]), ECLAMP);
                float hv = (1.0f - ec) *
                           __builtin_amdgcn_rcpf((1.0f + eo) * (1.0f + ec));
                const int row = quad * 4 + e;
                hw2[row * HSTR + col] = (_Float16)hv;
                if (t == SEQ - 1) h2f[row * 132 + col] = hv;   // f32 final hidden for FC
            }
            // burst next chunk's p-gates (after epilogue consumed pg[3]; LDS for
            // chunk base t+1 was staged at s==2 with a barrier in between)
            if (s == 3 && t + 1 < SEQ) pburst(t + 1);
            __syncthreads();
        }
    }

    // ---------------- FC epilogue (overwrites this tile's flag slot last) ----------------
    if (tid < 160) {
        const int cls = tid >> 4, b = tid & 15;
        float a = fc_b[cls];
        const float* wr = fc_w + cls * HID;
#pragma unroll 8
        for (int k = 0; k < HID; ++k) a += wr[k] * h2f[b * 132 + k];
        out[(size_t)(b0 + b) * 10 + cls] = a;
    }
}

extern "C" void kernel_launch(void* const* d_in, const int* in_sizes, int n_in,
                              void* d_out, int out_size, void* d_ws, size_t ws_size,
                              hipStream_t stream) {
    (void)in_sizes; (void)n_in; (void)out_size; (void)ws_size;
    const float* x     = (const float*)d_in[0];
    const float* w_ih0 = (const float*)d_in[1];
    const float* w_hh0 = (const float*)d_in[2];
    const float* b_ih0 = (const float*)d_in[3];
    const float* b_hh0 = (const float*)d_in[4];
    const float* w_ih1 = (const float*)d_in[5];
    const float* w_hh1 = (const float*)d_in[6];
    const float* b_ih1 = (const float*)d_in[7];
    const float* b_hh1 = (const float*)d_in[8];
    const float* fc_w  = (const float*)d_in[9];
    const float* fc_b  = (const float*)d_in[10];
    float* out = (float*)d_out;
    _Float16* h1w = (_Float16*)d_ws;   // 16 tiles * 512*16*128 fp16 = 32 MiB

    // zero out[] first: its first 4B of each batch-tile row-block doubles as the
    // producer->consumer chunk flag (stream-ordered, graph-capture safe)
    hipMemsetAsync(d_out, 0, BATCH * 10 * sizeof(float), stream);
    lstm_fused<<<2 * NBLK, NTHR, 0, stream>>>(x, w_ih0, w_hh0, b_ih0, b_hh0,
                                              w_ih1, w_hh1, b_ih1, b_hh1,
                                              fc_w, fc_b, out, h1w);
}

// Round 9
// 588.399 us; speedup vs baseline: 1.0672x; 1.0672x over previous
//
#include <hip/hip_runtime.h>

#define HID   128
#define GATES 512
#define BATCH 256
#define SEQ   512
#define INSZ  10
#define MB    16                 // batch rows per block (MFMA M)
#define NBLK  (BATCH / MB)       // 16 producer blocks + 16 consumer blocks
#define NTHR  512                // 8 waves
#define HSTR  136                // fp16 row stride for h buffers (bank-conflict pad, 16B-aligned rows)
#define XSTR  40                 // fp16 row stride for x staging (K padded 10->32, +8 pad)
#define XCH   8                  // x chunk (steps) phase A
#define HCH   4                  // h1 chunk (steps) phase B
#define PCH   8                  // producer publish granularity (steps per flag update)

typedef _Float16 half8  __attribute__((ext_vector_type(8)));
typedef _Float16 half2v __attribute__((ext_vector_type(2)));
typedef float    floatx4 __attribute__((ext_vector_type(4)));

#define MFMA16(A, B, C) __builtin_amdgcn_mfma_f32_16x16x32_f16(A, B, C, 0, 0, 0)

// Gate scales folded into weights+biases: accumulator holds the ready exp2 arg.
//   i,f,o: a = -log2e * pre      -> sigm = rcp(1+exp2(a))
//   g:     a = -2*log2e * pre    -> tanh = 2*rcp(1+exp2(a)) - 1
#define KSIG  (-1.4426950408889634f)
#define KTAN  (-2.8853900817779268f)

__device__ __forceinline__ float sigm_pre(float a)
{
    return __builtin_amdgcn_rcpf(1.0f + __builtin_amdgcn_exp2f(a));
}
__device__ __forceinline__ float tanh_pre(float a)
{
    return __builtin_fmaf(2.0f, __builtin_amdgcn_rcpf(1.0f + __builtin_amdgcn_exp2f(a)), -1.0f);
}
__device__ __forceinline__ float tanh_plain(float c)
{
    return tanh_pre(c * KTAN);
}

// convert 8 consecutive f32 weights (pre-scaled) to a half8 B-fragment
__device__ __forceinline__ half8 load_wfrag(const float* rowbase, int k0, float scale)
{
    const float4* p = (const float4*)(rowbase + k0);
    float4 a = p[0], b = p[1];
    half8 r;
    r[0] = (_Float16)(a.x * scale); r[1] = (_Float16)(a.y * scale);
    r[2] = (_Float16)(a.z * scale); r[3] = (_Float16)(a.w * scale);
    r[4] = (_Float16)(b.x * scale); r[5] = (_Float16)(b.y * scale);
    r[6] = (_Float16)(b.z * scale); r[7] = (_Float16)(b.w * scale);
    return r;
}

// ---- LDS layout (bytes) ----  (R4 layout)
// Producer: xs [2][XCH][MB][XSTR] fp16 @0 (20480 B), h0 [2][MB][HSTR] fp16 @20480 (8704 B)
// Consumer: h1c [2][HCH][MB][HSTR] fp16 @0 (34816 B), h2 [2][MB][HSTR] fp16 @34816 (8704 B)
// Final:    h2f [MB][132] f32 @0 (8448 B; only overlaps h1c buf0, dead by t=511)
#define XBUF_HALFS (XCH * MB * XSTR)      // 5120
#define H1C_BUF_HALFS (HCH * MB * HSTR)   // 8704
#define H0_OFF  20480
#define H2_OFF  34816
#define LDS_BYTES 43520

// Chunk-flag wait: relaxed device-scope spin, then one acquire to order the
// subsequent h1 loads against the producer's release. lastf caches the last
// observed value so steady-state polls are a register compare (no memory op).
__device__ __forceinline__ int wait_flag(int* flagp, int needed, int lastf)
{
    if (lastf >= needed) return lastf;
    int f = __hip_atomic_load(flagp, __ATOMIC_RELAXED, __HIP_MEMORY_SCOPE_AGENT);
    while (f < needed) {
        __builtin_amdgcn_s_sleep(2);
        f = __hip_atomic_load(flagp, __ATOMIC_RELAXED, __HIP_MEMORY_SCOPE_AGENT);
    }
    (void)__hip_atomic_load(flagp, __ATOMIC_ACQUIRE, __HIP_MEMORY_SCOPE_AGENT);
    return f;
}

__global__ __launch_bounds__(NTHR, 2)
void lstm_fused(const float* __restrict__ x,
                const float* __restrict__ w_ih0, const float* __restrict__ w_hh0,
                const float* __restrict__ b_ih0, const float* __restrict__ b_hh0,
                const float* __restrict__ w_ih1, const float* __restrict__ w_hh1,
                const float* __restrict__ b_ih1, const float* __restrict__ b_hh1,
                const float* __restrict__ fc_w,  const float* __restrict__ fc_b,
                float* __restrict__ out, _Float16* __restrict__ h1w_all)
{
    const int tid  = threadIdx.x;
    const int lane = tid & 63;
    const int wv   = tid >> 6;        // wave 0..7 -> hidden cols [16wv,16wv+16)
    const int m16  = lane & 15;       // MFMA row (batch) / col-in-tile
    const int quad = lane >> 4;       // 0..3
    const int col  = (wv << 4) + m16; // hidden col 0..127

    const bool producer = (blockIdx.x < NBLK);
    const int  pb = producer ? blockIdx.x : blockIdx.x - NBLK;  // batch-tile id
    const int  b0 = pb * MB;

    __shared__ __align__(16) char lds[LDS_BYTES];
    _Float16* xs  = (_Float16*)lds;
    _Float16* h0s = (_Float16*)(lds + H0_OFF);
    _Float16* h1c = (_Float16*)lds;
    _Float16* h2s = (_Float16*)(lds + H2_OFF);
    float*    h2f = (float*)lds;

    _Float16* h1w = h1w_all + (size_t)pb * SEQ * MB * HID;
    // flag parked inside this tile's out rows (host memsets out to 0 pre-launch);
    // consumer pb's FC epilogue overwrites it only after its last poll.
    int* flagp = (int*)out + pb * (MB * 10);

    const float gsc[4] = {KSIG, KSIG, KTAN, KSIG};   // i, f, g, o

    if (producer) {
        // ---------------- layer-0 weight fragments (pre-scaled) ----------------
        half8 Whh0f[4][4];   // [gate][kslice]  B[k][n]: n=lane&15 within tile, k=32ks+8quad+j
        half8 Wih0f[4];      // K=32 padded from 10
        float bias0[4];
#pragma unroll
        for (int g = 0; g < 4; ++g) {
            const int gr = g * HID + col;
            const float sc = gsc[g];
            bias0[g] = (b_ih0[gr] + b_hh0[gr]) * sc;
#pragma unroll
            for (int ks = 0; ks < 4; ++ks)
                Whh0f[g][ks] = load_wfrag(w_hh0 + (size_t)gr * HID, ks * 32 + quad * 8, sc);
            half8 r;
#pragma unroll
            for (int j = 0; j < 8; ++j) {
                int k = quad * 8 + j;
                r[j] = (k < INSZ) ? (_Float16)(w_ih0[gr * INSZ + k] * sc) : (_Float16)0.0f;
            }
            Wih0f[g] = r;
        }

        // zero x (both bufs incl. k>=10 pad) and h0 (both bufs)
        for (int i = tid; i < (H0_OFF + 8704) / 4; i += NTHR) ((int*)lds)[i] = 0;

        // stage x chunk 0 (threads 0..127, one (step,batch) row each)
        if (tid < 128) {
            const int sr = tid >> 4, mr = tid & 15;
            const float2* xp = (const float2*)(x + ((size_t)(b0 + mr) * SEQ + sr) * INSZ);
            _Float16* dst = xs + (sr * MB + mr) * XSTR;
#pragma unroll
            for (int p = 0; p < 5; ++p) {
                float2 v = xp[p];
                half2v h; h[0] = (_Float16)v.x; h[1] = (_Float16)v.y;
                *(half2v*)(dst + 2 * p) = h;
            }
        }
        __syncthreads();

        // ---------------- layer-0 recurrence ----------------
        float c0[4] = {0.f, 0.f, 0.f, 0.f};
        float2 xr[5];
        floatx4 xg[4][4];    // [slot][gate] precomputed bias + x-part, then hh-accumulated
        // incremented h1w pointer: kills per-element 64-bit address mul
        _Float16* h1p = h1w + (size_t)(quad * 4) * HID + col;

        // burst: precompute the x-gates for steps base..base+3 (no recurrence dep,
        // deep MFMA pipeline, off the serial chain). slot k = (base+k)&3.
        auto xburst = [&](int base) {
            const _Float16* xb = xs + ((base >> 3) & 1) * XBUF_HALFS;
#pragma unroll
            for (int k = 0; k < 4; ++k) {
                half8 xa = *(const half8*)(xb + (((base & 7) + k) * MB + m16) * XSTR + quad * 8);
#pragma unroll
                for (int g = 0; g < 4; ++g) {
                    floatx4 a = {bias0[g], bias0[g], bias0[g], bias0[g]};
                    a = MFMA16(xa, Wih0f[g], a);
                    xg[k][g] = a;
                }
            }
        };
        xburst(0);

        for (int tc = 0; tc < SEQ; tc += 8) {
#pragma unroll
            for (int s8 = 0; s8 < 8; ++s8) {
                const int t = tc + s8;
                const int sl = s8 & 3;            // xg slot (static after unroll)
                // prefetch next x chunk into regs at s8==0, commit to LDS at s8==2
                if (s8 == 0 && t + XCH < SEQ && tid < 128) {
                    const int sr = tid >> 4, mr = tid & 15;
                    const float2* xp = (const float2*)(x + ((size_t)(b0 + mr) * SEQ + (t + XCH + sr)) * INSZ);
#pragma unroll
                    for (int p = 0; p < 5; ++p) xr[p] = xp[p];
                }
                // hh-part: 4-deep dependent chain per gate, C-init = precomputed xg
                const _Float16* hb = h0s + (s8 & 1) * (MB * HSTR) + m16 * HSTR + quad * 8;
                half8 ha0 = *(const half8*)(hb);
                half8 ha1 = *(const half8*)(hb + 32);
                half8 ha2 = *(const half8*)(hb + 64);
                half8 ha3 = *(const half8*)(hb + 96);
#pragma unroll
                for (int g = 0; g < 4; ++g) {
                    floatx4 a = xg[sl][g];
                    a = MFMA16(ha0, Whh0f[g][0], a);
                    a = MFMA16(ha1, Whh0f[g][1], a);
                    a = MFMA16(ha2, Whh0f[g][2], a);
                    a = MFMA16(ha3, Whh0f[g][3], a);
                    xg[sl][g] = a;
                }
                if (s8 == 2 && t + 6 < SEQ && tid < 128) {
                    const int sr = tid >> 4, mr = tid & 15;
                    _Float16* dst = xs + (((t >> 3) + 1) & 1) * XBUF_HALFS + (sr * MB + mr) * XSTR;
#pragma unroll
                    for (int p = 0; p < 5; ++p) {
                        half2v h; h[0] = (_Float16)xr[p].x; h[1] = (_Float16)xr[p].y;
                        *(half2v*)(dst + 2 * p) = h;
                    }
                }
                // epilogue: C layout col=lane&15 (=our col), row=quad*4+e
                _Float16* hw = h0s + ((s8 & 1) ^ 1) * (MB * HSTR);
                const bool doBurst = (s8 == 3 || s8 == 7) && (t + 4 < SEQ);
                if (doBurst) {
                    // fused epilogue + xburst(t+1): per element e, issue the burst
                    // ds_read first (latency hides under the trans VALU), then the
                    // epilogue VALU, then the 4 independent burst MFMAs (MFMA pipe
                    // runs under the next element's VALU — in-order issue overlap).
                    const _Float16* xb = xs + (((t + 1) >> 3) & 1) * XBUF_HALFS;
#pragma unroll
                    for (int e = 0; e < 4; ++e) {
                        half8 xa = *(const half8*)(xb + ((((t + 1) & 7) + e) * MB + m16) * XSTR + quad * 8);
                        float iv = sigm_pre(xg[sl][0][e]);
                        float fv = sigm_pre(xg[sl][1][e]);
                        float gv = tanh_pre(xg[sl][2][e]);
                        float ov = sigm_pre(xg[sl][3][e]);
                        c0[e] = __builtin_fmaf(fv, c0[e], iv * gv);
                        float hv = ov * tanh_plain(c0[e]);
                        _Float16 hh = (_Float16)hv;
                        hw[(quad * 4 + e) * HSTR + col] = hh;
                        h1p[(s8 * MB + e) * HID] = hh;
                        // burst quarter k=e (writes xg[e]; epilogue's xg[3][g][e]
                        // reads precede the e==3 overwrite — register-dep safe)
#pragma unroll
                        for (int g = 0; g < 4; ++g) {
                            floatx4 a = {bias0[g], bias0[g], bias0[g], bias0[g]};
                            a = MFMA16(xa, Wih0f[g], a);
                            xg[e][g] = a;
                        }
                    }
                } else {
#pragma unroll
                    for (int e = 0; e < 4; ++e) {
                        float iv = sigm_pre(xg[sl][0][e]);
                        float fv = sigm_pre(xg[sl][1][e]);
                        float gv = tanh_pre(xg[sl][2][e]);
                        float ov = sigm_pre(xg[sl][3][e]);
                        c0[e] = __builtin_fmaf(fv, c0[e], iv * gv);
                        float hv = ov * tanh_plain(c0[e]);
                        _Float16 hh = (_Float16)hv;
                        hw[(quad * 4 + e) * HSTR + col] = hh;
                        h1p[(s8 * MB + e) * HID] = hh;
                    }
                }
                __syncthreads();
                // publish: syncthreads drained all waves' h1w stores for steps <= t
                if (s8 == 7 && tid == 0) {
                    __threadfence();   // XCD L2 writeback -> device-visible
                    __hip_atomic_store(flagp, t + 1, __ATOMIC_RELEASE, __HIP_MEMORY_SCOPE_AGENT);
                }
            }
            h1p += 8 * MB * HID;
        }
        return;
    }

    // ================= consumer: layer 1 =================
    half8 Wih1f[4][4], Whh1f[4][4];
    float bias1[4];
#pragma unroll
    for (int g = 0; g < 4; ++g) {
        const int gr = g * HID + col;
        const float sc = gsc[g];
        bias1[g] = (b_ih1[gr] + b_hh1[gr]) * sc;
#pragma unroll
        for (int ks = 0; ks < 4; ++ks) {
            Wih1f[g][ks] = load_wfrag(w_ih1 + (size_t)gr * HID, ks * 32 + quad * 8, sc);
            Whh1f[g][ks] = load_wfrag(w_hh1 + (size_t)gr * HID, ks * 32 + quad * 8, sc);
        }
    }
    // zero h2 state bufs
    for (int i = tid; i < 2176; i += NTHR) ((int*)(lds + H2_OFF))[i] = 0;

    // per-thread staging offsets (constant over the loop)
    const int ef0 = tid * 8, ef1 = (tid + NTHR) * 8;
    const int so0 = ((ef0 >> 11) * MB + ((ef0 & 2047) >> 7)) * HSTR + (ef0 & 127);
    const int so1 = ((ef1 >> 11) * MB + ((ef1 & 2047) >> 7)) * HSTR + (ef1 & 127);

    int lastf = 0;
    lastf = wait_flag(flagp, 8, lastf);   // steps 0..7 available (need 0..3)

    // stage h1 chunk 0
    {
        int4 a0v = *(const int4*)(h1w + ef0);
        int4 a1v = *(const int4*)(h1w + ef1);
        *(int4*)(h1c + so0) = a0v;
        *(int4*)(h1c + so1) = a1v;
    }
    __syncthreads();

    floatx4 pg[4][4];    // [slot][gate] precomputed bias + p-part, then q-accumulated
    const int prb = m16 * HSTR + quad * 8;

    // burst: xg1 = bias + h1[base+k] @ W_ih1^T for the 4 steps of a chunk.
    auto pburst = [&](int base) {
        const _Float16* sb = h1c + ((base >> 2) & 1) * H1C_BUF_HALFS;
#pragma unroll
        for (int k = 0; k < 4; ++k) {
            const _Float16* pp = sb + (k * MB + m16) * HSTR + prb - m16 * HSTR;  // == sb + (k*MB+m16)*HSTR + quad*8
            half8 f0 = *(const half8*)(pp);
            half8 f1 = *(const half8*)(pp + 32);
            half8 f2 = *(const half8*)(pp + 64);
            half8 f3 = *(const half8*)(pp + 96);
#pragma unroll
            for (int g = 0; g < 4; ++g) {
                floatx4 a = {bias1[g], bias1[g], bias1[g], bias1[g]};
                a = MFMA16(f0, Wih1f[g][0], a);
                a = MFMA16(f1, Wih1f[g][1], a);
                a = MFMA16(f2, Wih1f[g][2], a);
                a = MFMA16(f3, Wih1f[g][3], a);
                pg[k][g] = a;
            }
        }
    };
    pburst(0);

    float c1[4] = {0.f, 0.f, 0.f, 0.f};
    int4 hr0, hr1;
    for (int tc = 0; tc < SEQ; tc += 4) {
#pragma unroll
        for (int s = 0; s < 4; ++s) {
            const int t = tc + s;
            if (s == 0 && t + HCH < SEQ) {
                lastf = wait_flag(flagp, t + 2 * HCH, lastf);   // producer done through step t+7
                const _Float16* src = h1w + (size_t)((t >> 2) + 1) * (HCH * MB * HID);
                hr0 = *(const int4*)(src + ef0);
                hr1 = *(const int4*)(src + ef1);
            }
            // q-part: 4-deep dependent chain per gate, C-init = precomputed pg
            const _Float16* h2b = h2s + (s & 1) * (MB * HSTR) + m16 * HSTR + quad * 8;
            half8 q0 = *(const half8*)(h2b);
            half8 q1 = *(const half8*)(h2b + 32);
            half8 q2 = *(const half8*)(h2b + 64);
            half8 q3 = *(const half8*)(h2b + 96);
#pragma unroll
            for (int g = 0; g < 4; ++g) {
                floatx4 a = pg[s][g];
                a = MFMA16(q0, Whh1f[g][0], a);
                a = MFMA16(q1, Whh1f[g][1], a);
                a = MFMA16(q2, Whh1f[g][2], a);
                a = MFMA16(q3, Whh1f[g][3], a);
                pg[s][g] = a;
            }
            if (s == 2 && t + 2 < SEQ) {
                _Float16* dstb = h1c + (((t >> 2) + 1) & 1) * H1C_BUF_HALFS;
                *(int4*)(dstb + so0) = hr0;
                *(int4*)(dstb + so1) = hr1;
            }
            _Float16* hw2 = h2s + ((s & 1) ^ 1) * (MB * HSTR);
            const bool doBurst = (s == 3) && (t + 1 < SEQ);
            if (doBurst) {
                // fused epilogue + pburst(t+1): burst ds_read issued first (hides
                // under trans VALU), 4 independent MFMAs after each element's VALU.
                const _Float16* sb = h1c + (((t + 1) >> 2) & 1) * H1C_BUF_HALFS;
#pragma unroll
                for (int e = 0; e < 4; ++e) {
                    const _Float16* pp = sb + (e * MB + m16) * HSTR + quad * 8;
                    half8 f0 = *(const half8*)(pp);
                    half8 f1 = *(const half8*)(pp + 32);
                    half8 f2 = *(const half8*)(pp + 64);
                    half8 f3 = *(const half8*)(pp + 96);
                    float iv = sigm_pre(pg[3][0][e]);
                    float fv = sigm_pre(pg[3][1][e]);
                    float gv = tanh_pre(pg[3][2][e]);
                    float ov = sigm_pre(pg[3][3][e]);
                    c1[e] = __builtin_fmaf(fv, c1[e], iv * gv);
                    float hv = ov * tanh_plain(c1[e]);
                    hw2[(quad * 4 + e) * HSTR + col] = (_Float16)hv;
                    // burst quarter k=e (writes pg[e]; pg[3][g][e] reads precede
                    // the e==3 overwrite — register-dep safe)
#pragma unroll
                    for (int g = 0; g < 4; ++g) {
                        floatx4 a = {bias1[g], bias1[g], bias1[g], bias1[g]};
                        a = MFMA16(f0, Wih1f[g][0], a);
                        a = MFMA16(f1, Wih1f[g][1], a);
                        a = MFMA16(f2, Wih1f[g][2], a);
                        a = MFMA16(f3, Wih1f[g][3], a);
                        pg[e][g] = a;
                    }
                }
            } else {
#pragma unroll
                for (int e = 0; e < 4; ++e) {
                    float iv = sigm_pre(pg[s][0][e]);
                    float fv = sigm_pre(pg[s][1][e]);
                    float gv = tanh_pre(pg[s][2][e]);
                    float ov = sigm_pre(pg[s][3][e]);
                    c1[e] = __builtin_fmaf(fv, c1[e], iv * gv);
                    float hv = ov * tanh_plain(c1[e]);
                    const int row = quad * 4 + e;
                    hw2[row * HSTR + col] = (_Float16)hv;
                    if (t == SEQ - 1) h2f[row * 132 + col] = hv;   // f32 final hidden for FC
                }
            }
            __syncthreads();
        }
    }

    // ---------------- FC epilogue (overwrites this tile's flag slot last) ----------------
    if (tid < 160) {
        const int cls = tid >> 4, b = tid & 15;
        float a = fc_b[cls];
        const float* wr = fc_w + cls * HID;
#pragma unroll 8
        for (int k = 0; k < HID; ++k) a += wr[k] * h2f[b * 132 + k];
        out[(size_t)(b0 + b) * 10 + cls] = a;
    }
}

extern "C" void kernel_launch(void* const* d_in, const int* in_sizes, int n_in,
                              void* d_out, int out_size, void* d_ws, size_t ws_size,
                              hipStream_t stream) {
    (void)in_sizes; (void)n_in; (void)out_size; (void)ws_size;
    const float* x     = (const float*)d_in[0];
    const float* w_ih0 = (const float*)d_in[1];
    const float* w_hh0 = (const float*)d_in[2];
    const float* b_ih0 = (const float*)d_in[3];
    const float* b_hh0 = (const float*)d_in[4];
    const float* w_ih1 = (const float*)d_in[5];
    const float* w_hh1 = (const float*)d_in[6];
    const float* b_ih1 = (const float*)d_in[7];
    const float* b_hh1 = (const float*)d_in[8];
    const float* fc_w  = (const float*)d_in[9];
    const float* fc_b  = (const float*)d_in[10];
    float* out = (float*)d_out;
    _Float16* h1w = (_Float16*)d_ws;   // 16 tiles * 512*16*128 fp16 = 32 MiB

    // zero out[] first: its first 4B of each batch-tile row-block doubles as the
    // producer->consumer chunk flag (stream-ordered, graph-capture safe)
    hipMemsetAsync(d_out, 0, BATCH * 10 * sizeof(float), stream);
    lstm_fused<<<2 * NBLK, NTHR, 0, stream>>>(x, w_ih0, w_hh0, b_ih0, b_hh0,
                                              w_ih1, w_hh1, b_ih1, b_hh1,
                                              fc_w, fc_b, out, h1w);
}